// Round 1
// 691.857 us; speedup vs baseline: 1.0415x; 1.0415x over previous
//
#include <hip/hip_runtime.h>
#include <math.h>

#define TBL   (1u << 19)
#define TMASK (TBL - 1u)
#define PRIME1 2654435761u
#define PRIME2 805459861u

typedef float v2f __attribute__((ext_vector_type(2)));
typedef float v4f __attribute__((ext_vector_type(4)));

struct LevelParams {
    float    scale[16];
    unsigned res[16];
    unsigned dense[16];
};

__device__ __forceinline__ void corner_indices(
    float x, float y, float z, float s, unsigned res, unsigned dense,
    unsigned idx[8], float* wx, float* wy, float* wz)
{
    float px = __fadd_rn(__fmul_rn(x, s), 0.5f);
    float py = __fadd_rn(__fmul_rn(y, s), 0.5f);
    float pz = __fadd_rn(__fmul_rn(z, s), 0.5f);
    float fx = floorf(px), fy = floorf(py), fz = floorf(pz);
    *wx = px - fx; *wy = py - fy; *wz = pz - fz;
    unsigned gx = (unsigned)fx, gy = (unsigned)fy, gz = (unsigned)fz;

    if (dense) {
        const unsigned rm1 = res - 1u;
        unsigned cx0 = min(gx, rm1),   cx1 = min(gx + 1u, rm1);
        unsigned cy0 = min(gy, rm1),   cy1 = min(gy + 1u, rm1);
        unsigned cz0 = min(gz, rm1),   cz1 = min(gz + 1u, rm1);
        unsigned y0 = cy0 * res,       y1 = cy1 * res;
        unsigned z0 = cz0 * res * res, z1 = cz1 * res * res;
        idx[0] = cx0 + y0 + z0;  idx[1] = cx0 + y0 + z1;
        idx[2] = cx0 + y1 + z0;  idx[3] = cx0 + y1 + z1;
        idx[4] = cx1 + y0 + z0;  idx[5] = cx1 + y0 + z1;
        idx[6] = cx1 + y1 + z0;  idx[7] = cx1 + y1 + z1;
    } else {
        unsigned hx0 = gx,          hx1 = gx + 1u;
        unsigned hy0 = gy * PRIME1, hy1 = hy0 + PRIME1;
        unsigned hz0 = gz * PRIME2, hz1 = hz0 + PRIME2;
        idx[0] = (hx0 ^ hy0 ^ hz0) & TMASK;
        idx[1] = (hx0 ^ hy0 ^ hz1) & TMASK;
        idx[2] = (hx0 ^ hy1 ^ hz0) & TMASK;
        idx[3] = (hx0 ^ hy1 ^ hz1) & TMASK;
        idx[4] = (hx1 ^ hy0 ^ hz0) & TMASK;
        idx[5] = (hx1 ^ hy0 ^ hz1) & TMASK;
        idx[6] = (hx1 ^ hy1 ^ hz0) & TMASK;
        idx[7] = (hx1 ^ hy1 ^ hz1) & TMASK;
    }
}

// Branchless paired gather: each corner loads the aligned 16B entry-pair
// containing it (tab4[idx>>1]) and selects by idx&1. For hashed levels with
// even gx, the x0/x1 corners hit the SAME 16B address (h and h^1); for dense
// levels the x-pair is adjacent (idx, idx+1) and shares the line half the
// time. Issuing the pair back-to-back guarantees the second access merges
// with the first miss instead of allocating a new one. Dense slices are
// padded to TBL entries, so reading idx|1 is always in-bounds; the unused
// entry is discarded by the select.
__device__ __forceinline__ v2f interp_level(
    const v4f* __restrict__ tab4,
    float x, float y, float z, float s, unsigned res, unsigned dense)
{
    unsigned idx[8];
    float wx, wy, wz;
    corner_indices(x, y, z, s, res, dense, idx, &wx, &wy, &wz);

    float wx0 = 1.f - wx, wy0 = 1.f - wy, wz0 = 1.f - wz;
    float wyz00 = wy0 * wz0, wyz01 = wy0 * wz;
    float wyz10 = wy  * wz0, wyz11 = wy  * wz;
    float cw0[4] = { wx0 * wyz00, wx0 * wyz01, wx0 * wyz10, wx0 * wyz11 };
    float cw1[4] = { wx  * wyz00, wx  * wyz01, wx  * wyz10, wx  * wyz11 };

    float f0 = 0.f, f1 = 0.f;
    #pragma unroll
    for (int k = 0; k < 4; ++k) {
        unsigned i0 = idx[k], i1 = idx[k + 4];      // x0 / x1 corner pair
        v4f q0 = tab4[i0 >> 1];
        v4f q1 = tab4[i1 >> 1];
        float a0 = (i0 & 1u) ? q0.z : q0.x;
        float b0 = (i0 & 1u) ? q0.w : q0.y;
        float a1 = (i1 & 1u) ? q1.z : q1.x;
        float b1 = (i1 & 1u) ? q1.w : q1.y;
        f0 = fmaf(cw0[k], a0, f0);
        f1 = fmaf(cw0[k], b0, f1);
        f0 = fmaf(cw1[k], a1, f0);
        f1 = fmaf(cw1[k], b1, f1);
    }
    v2f r; r.x = f0; r.y = f1;
    return r;
}

// ---------- Pass A: level-major compute, coalesced nt-stores into ws ----------
__global__ __launch_bounds__(256, 8) void pass_a(
    const float* __restrict__ coords,
    const float* __restrict__ table,
    v2f* __restrict__ ws,            // [16][N] float2, level-major
    LevelParams lp, unsigned n)
{
    const unsigned l = blockIdx.y;
    const unsigned p = blockIdx.x * 256u + threadIdx.x;
    if (p >= n) return;

    const float x = coords[3ull * p + 0];
    const float y = coords[3ull * p + 1];
    const float z = coords[3ull * p + 2];

    const v4f* __restrict__ tab4 = (const v4f*)(table + (size_t)l * (2u * TBL));
    v2f r = interp_level(tab4, x, y, z, lp.scale[l], lp.res[l], lp.dense[l]);
    __builtin_nontemporal_store(r, ws + (size_t)l * n + p);
}

// ---------- Pass B: ws[16][N] float2 -> out[N][32] transpose ----------
// LDS-free: each thread owns one point. 16 coalesced dwordx2 loads (wave reads
// 512B contiguous per level), assemble 8 float4 in registers, store the 128B
// output row directly. Stores are lane-strided (partial lines) but each lane
// writes all 4 sectors of its 2 lines back-to-back -> L2 write-back merges.
// ~8M store line-touches total = ~16us of TA time; loads fully coalesced.
__global__ __launch_bounds__(256, 8) void pass_b(
    const v2f* __restrict__ ws,
    float* __restrict__ out, unsigned n)
{
    const unsigned p = blockIdx.x * 256u + threadIdx.x;
    if (p >= n) return;

    v2f v[16];
    #pragma unroll
    for (int l = 0; l < 16; ++l)
        v[l] = ws[(size_t)l * n + p];

    v4f* __restrict__ out4 = (v4f*)out;
    #pragma unroll
    for (int i = 0; i < 8; ++i) {
        v4f o;
        o.x = v[2 * i].x;     o.y = v[2 * i].y;
        o.z = v[2 * i + 1].x; o.w = v[2 * i + 1].y;
        out4[(size_t)p * 8u + i] = o;
    }
}

// ---------- Fallback: single-kernel (if ws too small) ----------
__global__ __launch_bounds__(256, 4) void hashgrid_enc(
    const float* __restrict__ coords,
    const float* __restrict__ table,
    float* __restrict__ out,
    LevelParams lp, unsigned n)
{
    __shared__ float lds[256 * 33];
    const unsigned t = threadIdx.x;
    const unsigned p = blockIdx.x * 256u + t;

    float x = 0.f, y = 0.f, z = 0.f;
    if (p < n) {
        x = coords[3ull * p + 0];
        y = coords[3ull * p + 1];
        z = coords[3ull * p + 2];
    }

    #pragma unroll 2
    for (int l = 0; l < 16; ++l) {
        const v4f* __restrict__ tab4 = (const v4f*)(table + (size_t)l * (2u * TBL));
        v2f r = interp_level(tab4, x, y, z, lp.scale[l], lp.res[l], lp.dense[l]);
        lds[t * 33u + 2u * l]      = r.x;
        lds[t * 33u + 2u * l + 1u] = r.y;
    }
    __syncthreads();

    const size_t base  = (size_t)blockIdx.x * 8192u;
    const size_t total = (size_t)n * 32u;
    #pragma unroll
    for (int i = 0; i < 32; ++i) {
        size_t j = (size_t)i * 256u + t;
        size_t o = base + j;
        if (o < total)
            out[o] = lds[(unsigned)(j >> 5) * 33u + ((unsigned)j & 31u)];
    }
}

extern "C" void kernel_launch(void* const* d_in, const int* in_sizes, int n_in,
                              void* d_out, int out_size, void* d_ws, size_t ws_size,
                              hipStream_t stream) {
    (void)n_in; (void)out_size;
    const float* coords = (const float*)d_in[0];
    const float* table  = (const float*)d_in[1];
    float* out = (float*)d_out;

    LevelParams lp;
    for (int l = 0; l < 16; ++l) {
        double scale = 16.0 * pow(1.4472692012786865, (double)l) - 1.0;
        int res = (int)ceil(scale) + 1;
        lp.scale[l] = (float)scale;
        lp.res[l]   = (unsigned)res;
        long long r3 = (long long)res * res * res;
        lp.dense[l] = (r3 <= (long long)TBL) ? 1u : 0u;
    }

    unsigned n = (unsigned)(in_sizes[0] / 3);
    unsigned chunks = (n + 255u) / 256u;
    size_t ws_needed = (size_t)16 * n * sizeof(v2f);

    if (ws_size >= ws_needed) {
        v2f* ws = (v2f*)d_ws;
        hipLaunchKernelGGL(pass_a, dim3(chunks, 16), dim3(256), 0, stream,
                           coords, table, ws, lp, n);
        hipLaunchKernelGGL(pass_b, dim3(chunks), dim3(256), 0, stream,
                           ws, out, n);
    } else {
        hipLaunchKernelGGL(hashgrid_enc, dim3(chunks), dim3(256), 0, stream,
                           coords, table, out, lp, n);
    }
}

// Round 4
// 662.634 us; speedup vs baseline: 1.0875x; 1.0441x over previous
//
#include <hip/hip_runtime.h>
#include <math.h>

#define TBL   (1u << 19)
#define TMASK (TBL - 1u)
#define PRIME1 2654435761u
#define PRIME2 805459861u

#define N_DENSE  5u   // levels 0..4: res^3 <= TBL, dense indexing, tables ~4MB total
#define N_HASH   11u  // levels 5..15: hashed

typedef float v2f __attribute__((ext_vector_type(2)));
typedef float v4f __attribute__((ext_vector_type(4)));

struct LevelParams {
    float    scale[16];
    unsigned res[16];
    unsigned dense[16];
};

__device__ __forceinline__ void corner_indices(
    float x, float y, float z, float s, unsigned res, unsigned dense,
    unsigned idx[8], float* wx, float* wy, float* wz)
{
    float px = __fadd_rn(__fmul_rn(x, s), 0.5f);
    float py = __fadd_rn(__fmul_rn(y, s), 0.5f);
    float pz = __fadd_rn(__fmul_rn(z, s), 0.5f);
    float fx = floorf(px), fy = floorf(py), fz = floorf(pz);
    *wx = px - fx; *wy = py - fy; *wz = pz - fz;
    unsigned gx = (unsigned)fx, gy = (unsigned)fy, gz = (unsigned)fz;

    if (dense) {
        const unsigned rm1 = res - 1u;
        unsigned cx0 = min(gx, rm1),   cx1 = min(gx + 1u, rm1);
        unsigned cy0 = min(gy, rm1),   cy1 = min(gy + 1u, rm1);
        unsigned cz0 = min(gz, rm1),   cz1 = min(gz + 1u, rm1);
        unsigned y0 = cy0 * res,       y1 = cy1 * res;
        unsigned z0 = cz0 * res * res, z1 = cz1 * res * res;
        idx[0] = cx0 + y0 + z0;  idx[1] = cx0 + y0 + z1;
        idx[2] = cx0 + y1 + z0;  idx[3] = cx0 + y1 + z1;
        idx[4] = cx1 + y0 + z0;  idx[5] = cx1 + y0 + z1;
        idx[6] = cx1 + y1 + z0;  idx[7] = cx1 + y1 + z1;
    } else {
        unsigned hx0 = gx,          hx1 = gx + 1u;
        unsigned hy0 = gy * PRIME1, hy1 = hy0 + PRIME1;
        unsigned hz0 = gz * PRIME2, hz1 = hz0 + PRIME2;
        idx[0] = (hx0 ^ hy0 ^ hz0) & TMASK;
        idx[1] = (hx0 ^ hy0 ^ hz1) & TMASK;
        idx[2] = (hx0 ^ hy1 ^ hz0) & TMASK;
        idx[3] = (hx0 ^ hy1 ^ hz1) & TMASK;
        idx[4] = (hx1 ^ hy0 ^ hz0) & TMASK;
        idx[5] = (hx1 ^ hy0 ^ hz1) & TMASK;
        idx[6] = (hx1 ^ hy1 ^ hz0) & TMASK;
        idx[7] = (hx1 ^ hy1 ^ hz1) & TMASK;
    }
}

// Paired 16B gather: each corner loads the aligned 16B entry-pair containing
// it (tab4[idx>>1]) and selects by idx&1. x0/x1 pairs share a line for even
// gx (hashed) / adjacent entries (dense); back-to-back issue guarantees MSHR
// merge. Always in-bounds: every level slice spans TBL entries.
__device__ __forceinline__ v2f interp_level(
    const v4f* __restrict__ tab4,
    float x, float y, float z, float s, unsigned res, unsigned dense)
{
    unsigned idx[8];
    float wx, wy, wz;
    corner_indices(x, y, z, s, res, dense, idx, &wx, &wy, &wz);

    float wx0 = 1.f - wx, wy0 = 1.f - wy, wz0 = 1.f - wz;
    float wyz00 = wy0 * wz0, wyz01 = wy0 * wz;
    float wyz10 = wy  * wz0, wyz11 = wy  * wz;
    float cw0[4] = { wx0 * wyz00, wx0 * wyz01, wx0 * wyz10, wx0 * wyz11 };
    float cw1[4] = { wx  * wyz00, wx  * wyz01, wx  * wyz10, wx  * wyz11 };

    float f0 = 0.f, f1 = 0.f;
    #pragma unroll
    for (int k = 0; k < 4; ++k) {
        unsigned i0 = idx[k], i1 = idx[k + 4];      // x0 / x1 corner pair
        v4f q0 = tab4[i0 >> 1];
        v4f q1 = tab4[i1 >> 1];
        float a0 = (i0 & 1u) ? q0.z : q0.x;
        float b0 = (i0 & 1u) ? q0.w : q0.y;
        float a1 = (i1 & 1u) ? q1.z : q1.x;
        float b1 = (i1 & 1u) ? q1.w : q1.y;
        f0 = fmaf(cw0[k], a0, f0);
        f1 = fmaf(cw0[k], b0, f1);
        f0 = fmaf(cw1[k], a1, f0);
        f1 = fmaf(cw1[k], b1, f1);
    }
    v2f r; r.x = f0; r.y = f1;
    return r;
}

// ---------- Pass A: hashed levels (5..15) only, level-major ----------
// Normal (cached) ws stores: ws (92MB) stays L3-resident for pass_b.
__global__ __launch_bounds__(256, 8) void pass_a(
    const float* __restrict__ coords,
    const float* __restrict__ table,
    v2f* __restrict__ ws,            // [11][N] float2, level-major
    LevelParams lp, unsigned n)
{
    const unsigned li = blockIdx.y;          // 0..10
    const unsigned l  = li + N_DENSE;        // 5..15, all hashed
    const unsigned p  = blockIdx.x * 256u + threadIdx.x;
    if (p >= n) return;

    const float x = coords[3ull * p + 0];
    const float y = coords[3ull * p + 1];
    const float z = coords[3ull * p + 2];

    const v4f* __restrict__ tab4 = (const v4f*)(table + (size_t)l * (2u * TBL));
    v2f r = interp_level(tab4, x, y, z, lp.scale[l], lp.res[l], 0u);
    ws[(size_t)li * n + p] = r;
}

// ---------- Pass B: dense levels computed + hashed from ws, LDS transpose ----
__global__ __launch_bounds__(256, 4) void pass_b(
    const float* __restrict__ coords,
    const float* __restrict__ table,
    const v2f* __restrict__ ws,
    float* __restrict__ out,
    LevelParams lp, unsigned n)
{
    __shared__ float lds[256 * 33];
    const unsigned t  = threadIdx.x;
    const unsigned p0 = blockIdx.x * 256u;
    const unsigned p  = p0 + t;

    float x = 0.f, y = 0.f, z = 0.f;
    if (p < n) {
        x = coords[3ull * p + 0];
        y = coords[3ull * p + 1];
        z = coords[3ull * p + 2];
    }

    // dense levels 0..4: tables total ~4MB, L2/L3-resident -> cheap gathers
    #pragma unroll
    for (int l = 0; l < (int)N_DENSE; ++l) {
        v2f r = {0.f, 0.f};
        if (p < n) {
            const v4f* __restrict__ tab4 =
                (const v4f*)(table + (size_t)l * (2u * TBL));
            r = interp_level(tab4, x, y, z, lp.scale[l], lp.res[l], 1u);
        }
        lds[t * 33u + 2u * l]      = r.x;
        lds[t * 33u + 2u * l + 1u] = r.y;
    }

    // hashed levels 5..15 from ws (L3-resident), coalesced cached loads
    #pragma unroll
    for (int l = 0; l < (int)N_HASH; ++l) {
        v2f v = {0.f, 0.f};
        if (p < n) v = ws[(size_t)l * n + p];
        lds[t * 33u + 2u * (l + N_DENSE)]      = v.x;
        lds[t * 33u + 2u * (l + N_DENSE) + 1u] = v.y;
    }
    __syncthreads();

    // coalesced NT v4f stores: 8 per thread
    v4f* __restrict__ out4 = (v4f*)out;
    const size_t base4  = (size_t)p0 * 8u;
    const size_t total4 = (size_t)n * 8u;
    #pragma unroll
    for (int i = 0; i < 8; ++i) {
        unsigned j = (unsigned)i * 256u + t;   // v4f index within block tile
        size_t o = base4 + j;
        if (o < total4) {
            unsigned pt = j >> 3, c = (j & 7u) * 4u;
            v4f q;
            q.x = lds[pt * 33u + c + 0u];
            q.y = lds[pt * 33u + c + 1u];
            q.z = lds[pt * 33u + c + 2u];
            q.w = lds[pt * 33u + c + 3u];
            __builtin_nontemporal_store(q, out4 + o);
        }
    }
}

// ---------- Fallback: single-kernel (if ws too small) ----------
__global__ __launch_bounds__(256, 4) void hashgrid_enc(
    const float* __restrict__ coords,
    const float* __restrict__ table,
    float* __restrict__ out,
    LevelParams lp, unsigned n)
{
    __shared__ float lds[256 * 33];
    const unsigned t = threadIdx.x;
    const unsigned p = blockIdx.x * 256u + t;

    float x = 0.f, y = 0.f, z = 0.f;
    if (p < n) {
        x = coords[3ull * p + 0];
        y = coords[3ull * p + 1];
        z = coords[3ull * p + 2];
    }

    #pragma unroll 2
    for (int l = 0; l < 16; ++l) {
        const v4f* __restrict__ tab4 = (const v4f*)(table + (size_t)l * (2u * TBL));
        v2f r = interp_level(tab4, x, y, z, lp.scale[l], lp.res[l], lp.dense[l]);
        lds[t * 33u + 2u * l]      = r.x;
        lds[t * 33u + 2u * l + 1u] = r.y;
    }
    __syncthreads();

    const size_t base  = (size_t)blockIdx.x * 8192u;
    const size_t total = (size_t)n * 32u;
    #pragma unroll
    for (int i = 0; i < 32; ++i) {
        size_t j = (size_t)i * 256u + t;
        size_t o = base + j;
        if (o < total)
            out[o] = lds[(unsigned)(j >> 5) * 33u + ((unsigned)j & 31u)];
    }
}

extern "C" void kernel_launch(void* const* d_in, const int* in_sizes, int n_in,
                              void* d_out, int out_size, void* d_ws, size_t ws_size,
                              hipStream_t stream) {
    (void)n_in; (void)out_size;
    const float* coords = (const float*)d_in[0];
    const float* table  = (const float*)d_in[1];
    float* out = (float*)d_out;

    LevelParams lp;
    for (int l = 0; l < 16; ++l) {
        double scale = 16.0 * pow(1.4472692012786865, (double)l) - 1.0;
        int res = (int)ceil(scale) + 1;
        lp.scale[l] = (float)scale;
        lp.res[l]   = (unsigned)res;
        long long r3 = (long long)res * res * res;
        lp.dense[l] = (r3 <= (long long)TBL) ? 1u : 0u;
    }

    unsigned n = (unsigned)(in_sizes[0] / 3);
    unsigned chunks = (n + 255u) / 256u;
    size_t ws_needed = (size_t)N_HASH * n * sizeof(v2f);

    if (ws_size >= ws_needed) {
        v2f* ws = (v2f*)d_ws;
        hipLaunchKernelGGL(pass_a, dim3(chunks, N_HASH), dim3(256), 0, stream,
                           coords, table, ws, lp, n);
        hipLaunchKernelGGL(pass_b, dim3(chunks), dim3(256), 0, stream,
                           coords, table, ws, out, lp, n);
    } else {
        hipLaunchKernelGGL(hashgrid_enc, dim3(chunks), dim3(256), 0, stream,
                           coords, table, out, lp, n);
    }
}

// Round 5
// 659.090 us; speedup vs baseline: 1.0933x; 1.0054x over previous
//
#include <hip/hip_runtime.h>
#include <math.h>

#define TBL   (1u << 19)
#define TMASK (TBL - 1u)
#define PRIME1 2654435761u
#define PRIME2 805459861u

#define N_DENSE  5u   // levels 0..4: res^3 <= TBL (res(4)=71 -> 357911 entries)
#define N_HASH   11u  // levels 5..15: hashed, each table exactly 4MB

typedef float v2f __attribute__((ext_vector_type(2)));
typedef float v4f __attribute__((ext_vector_type(4)));

struct LevelParams {
    float    scale[16];
    unsigned res[16];
    unsigned dense[16];
};

__device__ __forceinline__ void corner_indices(
    float x, float y, float z, float s, unsigned res, unsigned dense,
    unsigned idx[8], float* wx, float* wy, float* wz)
{
    float px = __fadd_rn(__fmul_rn(x, s), 0.5f);
    float py = __fadd_rn(__fmul_rn(y, s), 0.5f);
    float pz = __fadd_rn(__fmul_rn(z, s), 0.5f);
    float fx = floorf(px), fy = floorf(py), fz = floorf(pz);
    *wx = px - fx; *wy = py - fy; *wz = pz - fz;
    unsigned gx = (unsigned)fx, gy = (unsigned)fy, gz = (unsigned)fz;

    if (dense) {
        const unsigned rm1 = res - 1u;
        unsigned cx0 = min(gx, rm1),   cx1 = min(gx + 1u, rm1);
        unsigned cy0 = min(gy, rm1),   cy1 = min(gy + 1u, rm1);
        unsigned cz0 = min(gz, rm1),   cz1 = min(gz + 1u, rm1);
        unsigned y0 = cy0 * res,       y1 = cy1 * res;
        unsigned z0 = cz0 * res * res, z1 = cz1 * res * res;
        idx[0] = cx0 + y0 + z0;  idx[1] = cx0 + y0 + z1;
        idx[2] = cx0 + y1 + z0;  idx[3] = cx0 + y1 + z1;
        idx[4] = cx1 + y0 + z0;  idx[5] = cx1 + y0 + z1;
        idx[6] = cx1 + y1 + z0;  idx[7] = cx1 + y1 + z1;
    } else {
        unsigned hx0 = gx,          hx1 = gx + 1u;
        unsigned hy0 = gy * PRIME1, hy1 = hy0 + PRIME1;
        unsigned hz0 = gz * PRIME2, hz1 = hz0 + PRIME2;
        idx[0] = (hx0 ^ hy0 ^ hz0) & TMASK;
        idx[1] = (hx0 ^ hy0 ^ hz1) & TMASK;
        idx[2] = (hx0 ^ hy1 ^ hz0) & TMASK;
        idx[3] = (hx0 ^ hy1 ^ hz1) & TMASK;
        idx[4] = (hx1 ^ hy0 ^ hz0) & TMASK;
        idx[5] = (hx1 ^ hy0 ^ hz1) & TMASK;
        idx[6] = (hx1 ^ hy1 ^ hz0) & TMASK;
        idx[7] = (hx1 ^ hy1 ^ hz1) & TMASK;
    }
}

// Paired 16B gather: each corner loads the aligned 16B entry-pair containing
// it (tab4[idx>>1]) and selects by idx&1 (proven: R1 pass_a 544->477us).
__device__ __forceinline__ v2f interp_level(
    const v4f* __restrict__ tab4,
    float x, float y, float z, float s, unsigned res, unsigned dense)
{
    unsigned idx[8];
    float wx, wy, wz;
    corner_indices(x, y, z, s, res, dense, idx, &wx, &wy, &wz);

    float wx0 = 1.f - wx, wy0 = 1.f - wy, wz0 = 1.f - wz;
    float wyz00 = wy0 * wz0, wyz01 = wy0 * wz;
    float wyz10 = wy  * wz0, wyz11 = wy  * wz;
    float cw0[4] = { wx0 * wyz00, wx0 * wyz01, wx0 * wyz10, wx0 * wyz11 };
    float cw1[4] = { wx  * wyz00, wx  * wyz01, wx  * wyz10, wx  * wyz11 };

    float f0 = 0.f, f1 = 0.f;
    #pragma unroll
    for (int k = 0; k < 4; ++k) {
        unsigned i0 = idx[k], i1 = idx[k + 4];
        v4f q0 = tab4[i0 >> 1];
        v4f q1 = tab4[i1 >> 1];
        float a0 = (i0 & 1u) ? q0.z : q0.x;
        float b0 = (i0 & 1u) ? q0.w : q0.y;
        float a1 = (i1 & 1u) ? q1.z : q1.x;
        float b1 = (i1 & 1u) ? q1.w : q1.y;
        f0 = fmaf(cw0[k], a0, f0);
        f1 = fmaf(cw0[k], b0, f1);
        f0 = fmaf(cw1[k], a1, f0);
        f1 = fmaf(cw1[k], b1, f1);
    }
    v2f r; r.x = f0; r.y = f1;
    return r;
}

// ---------- Pass A1: hashed levels 5..12, ONE LEVEL PER XCD ----------
// gfx950 dispatches consecutive blockIdx round-robin across the 8 XCDs, so
// level = 5 + (blockIdx.x & 7) pins each level's gathers to one XCD whose
// 4MB L2 exactly holds that level's table -> L2-hit (~200cy) instead of
// L3 (~450+cy), doubling MSHR-bound throughput. ws stores are NT to avoid
// evicting table lines. If the %8 mapping is wrong this degrades to the
// current behavior (perf-only assumption).
__global__ __launch_bounds__(256, 8) void pass_a1(
    const float* __restrict__ coords,
    const float* __restrict__ table,
    v2f* __restrict__ ws,            // [16][N] float2, level-major
    LevelParams lp, unsigned n)
{
    const unsigned b   = blockIdx.x;
    const unsigned l   = 5u + (b & 7u);      // levels 5..12
    const unsigned p   = (b >> 3) * 256u + threadIdx.x;
    if (p >= n) return;

    const float x = coords[3ull * p + 0];
    const float y = coords[3ull * p + 1];
    const float z = coords[3ull * p + 2];

    const v4f* __restrict__ tab4 = (const v4f*)(table + (size_t)l * (2u * TBL));
    v2f r = interp_level(tab4, x, y, z, lp.scale[l], lp.res[l], 0u);
    __builtin_nontemporal_store(r, ws + (size_t)l * n + p);
}

// ---------- Pass A2: hashed 13..15 + dense 0..4, full occupancy ----------
__global__ __launch_bounds__(256, 8) void pass_a2(
    const float* __restrict__ coords,
    const float* __restrict__ table,
    v2f* __restrict__ ws,
    LevelParams lp, unsigned n)
{
    const unsigned by = blockIdx.y;          // 0..7
    const unsigned l  = (by < 3u) ? (13u + by) : (by - 3u);
    const unsigned dn = (by < 3u) ? 0u : 1u;
    const unsigned p  = blockIdx.x * 256u + threadIdx.x;
    if (p >= n) return;

    const float x = coords[3ull * p + 0];
    const float y = coords[3ull * p + 1];
    const float z = coords[3ull * p + 2];

    const v4f* __restrict__ tab4 = (const v4f*)(table + (size_t)l * (2u * TBL));
    v2f r = interp_level(tab4, x, y, z, lp.scale[l], lp.res[l], dn);
    __builtin_nontemporal_store(r, ws + (size_t)l * n + p);
}

// ---------- Pass B: pure ws[16][N] -> out[N][32] transpose ----------
// 2-round register-held transpose: LDS halved to 128x33 floats (16.9KB)
// -> 8 blocks/CU (was 4). Each thread holds its point's 16 v2f in regs;
// round r has threads 128r..128r+127 deposit, all 256 store 128 rows.
__global__ __launch_bounds__(256, 8) void pass_b(
    const v2f* __restrict__ ws,
    float* __restrict__ out, unsigned n)
{
    __shared__ float lds[128 * 33];
    const unsigned t  = threadIdx.x;
    const unsigned p0 = blockIdx.x * 256u;
    const unsigned p  = p0 + t;

    v2f v[16];
    #pragma unroll
    for (int l = 0; l < 16; ++l) {
        v2f q = {0.f, 0.f};
        if (p < n) q = __builtin_nontemporal_load(ws + (size_t)l * n + p);
        v[l] = q;
    }

    v4f* __restrict__ out4 = (v4f*)out;
    const size_t total4 = (size_t)n * 8u;

    #pragma unroll
    for (int r = 0; r < 2; ++r) {
        __syncthreads();
        if ((t >> 7) == (unsigned)r) {
            const unsigned tt = t & 127u;
            #pragma unroll
            for (int l = 0; l < 16; ++l) {
                lds[tt * 33u + 2u * l]      = v[l].x;
                lds[tt * 33u + 2u * l + 1u] = v[l].y;
            }
        }
        __syncthreads();
        const size_t base4 = (size_t)(p0 + 128u * (unsigned)r) * 8u;
        #pragma unroll
        for (int i = 0; i < 4; ++i) {
            unsigned j = (unsigned)i * 256u + t;   // 0..1023 v4f within half-tile
            size_t o = base4 + j;
            if (o < total4) {
                unsigned pt = j >> 3, c = (j & 7u) * 4u;
                v4f q;
                q.x = lds[pt * 33u + c + 0u];
                q.y = lds[pt * 33u + c + 1u];
                q.z = lds[pt * 33u + c + 2u];
                q.w = lds[pt * 33u + c + 3u];
                __builtin_nontemporal_store(q, out4 + o);
            }
        }
    }
}

// ---------- Fallback: single-kernel (if ws too small) ----------
__global__ __launch_bounds__(256, 4) void hashgrid_enc(
    const float* __restrict__ coords,
    const float* __restrict__ table,
    float* __restrict__ out,
    LevelParams lp, unsigned n)
{
    __shared__ float lds[256 * 33];
    const unsigned t = threadIdx.x;
    const unsigned p = blockIdx.x * 256u + t;

    float x = 0.f, y = 0.f, z = 0.f;
    if (p < n) {
        x = coords[3ull * p + 0];
        y = coords[3ull * p + 1];
        z = coords[3ull * p + 2];
    }

    #pragma unroll 2
    for (int l = 0; l < 16; ++l) {
        const v4f* __restrict__ tab4 = (const v4f*)(table + (size_t)l * (2u * TBL));
        v2f r = interp_level(tab4, x, y, z, lp.scale[l], lp.res[l], lp.dense[l]);
        lds[t * 33u + 2u * l]      = r.x;
        lds[t * 33u + 2u * l + 1u] = r.y;
    }
    __syncthreads();

    const size_t base  = (size_t)blockIdx.x * 8192u;
    const size_t total = (size_t)n * 32u;
    #pragma unroll
    for (int i = 0; i < 32; ++i) {
        size_t j = (size_t)i * 256u + t;
        size_t o = base + j;
        if (o < total)
            out[o] = lds[(unsigned)(j >> 5) * 33u + ((unsigned)j & 31u)];
    }
}

extern "C" void kernel_launch(void* const* d_in, const int* in_sizes, int n_in,
                              void* d_out, int out_size, void* d_ws, size_t ws_size,
                              hipStream_t stream) {
    (void)n_in; (void)out_size;
    const float* coords = (const float*)d_in[0];
    const float* table  = (const float*)d_in[1];
    float* out = (float*)d_out;

    LevelParams lp;
    for (int l = 0; l < 16; ++l) {
        double scale = 16.0 * pow(1.4472692012786865, (double)l) - 1.0;
        int res = (int)ceil(scale) + 1;
        lp.scale[l] = (float)scale;
        lp.res[l]   = (unsigned)res;
        long long r3 = (long long)res * res * res;
        lp.dense[l] = (r3 <= (long long)TBL) ? 1u : 0u;
    }

    unsigned n = (unsigned)(in_sizes[0] / 3);
    unsigned chunks = (n + 255u) / 256u;
    size_t ws_needed = (size_t)16 * n * sizeof(v2f);

    if (ws_size >= ws_needed) {
        v2f* ws = (v2f*)d_ws;
        hipLaunchKernelGGL(pass_a1, dim3(chunks * 8u), dim3(256), 0, stream,
                           coords, table, ws, lp, n);
        hipLaunchKernelGGL(pass_a2, dim3(chunks, 8), dim3(256), 0, stream,
                           coords, table, ws, lp, n);
        hipLaunchKernelGGL(pass_b, dim3(chunks), dim3(256), 0, stream,
                           ws, out, n);
    } else {
        hipLaunchKernelGGL(hashgrid_enc, dim3(chunks), dim3(256), 0, stream,
                           coords, table, out, lp, n);
    }
}